// Round 1
// baseline (684.183 us; speedup 1.0000x reference)
//
#include <hip/hip_runtime.h>

// DIMKT: B=1024, S=200, D=128.
// Restructured: precompute projected embedding tables + x array (bf16),
// tiny corr/qd/cd gate-bias tables; scan does only 5 DxD matvecs/row/step
// via register-resident bf16 MFMA fragments. 64 blocks x 16 rows, no grid sync.

#define S_LEN 200
#define NBATCH 1024
#define DIM 128
#define LOG2E 1.4426950408889634f

typedef short short8 __attribute__((ext_vector_type(8)));
typedef float f32x4 __attribute__((ext_vector_type(4)));

__device__ __forceinline__ unsigned short f2b(float f) {
  union { float f; unsigned u; } v; v.f = f;
  unsigned r = (v.u + 0x7FFFu + ((v.u >> 16) & 1u)) >> 16;  // RNE
  return (unsigned short)r;
}
__device__ __forceinline__ float b2f(unsigned short b) {
  union { unsigned u; float f; } v; v.u = ((unsigned)b) << 16;
  return v.f;
}
__device__ __forceinline__ float fast_sigmoid(float x) {
  return __builtin_amdgcn_rcpf(1.0f + __builtin_amdgcn_exp2f(-LOG2E * x));
}
__device__ __forceinline__ float fast_tanh(float x) {
  return 2.0f * __builtin_amdgcn_rcpf(1.0f + __builtin_amdgcn_exp2f(-2.0f * LOG2E * x)) - 1.0f;
}

// ---------------- P1: projected embedding tables: T[r][o] = sum_k E[r][k] * W[o][coff+k]
__global__ void proj_table_kernel(const float* __restrict__ E, int M,
                                  const float* __restrict__ W, int ldw, int coff,
                                  unsigned short* __restrict__ T) {
  __shared__ __align__(16) float Elds[32][132];  // +4 pad, keeps float4 align
  const int r0 = blockIdx.x * 32;
  for (int idx = threadIdx.x; idx < 32 * 32; idx += 256) {
    const int r = idx >> 5, c4 = idx & 31;
    float4 v = {0.f, 0.f, 0.f, 0.f};
    if (r0 + r < M) v = *(const float4*)(E + (size_t)(r0 + r) * DIM + c4 * 4);
    *(float4*)&Elds[r][c4 * 4] = v;
  }
  __syncthreads();
  const int o = threadIdx.x & 127, rg = threadIdx.x >> 7;
  const float* Wrow = W + (size_t)o * ldw + coff;
  float acc[16];
#pragma unroll
  for (int i = 0; i < 16; ++i) acc[i] = 0.f;
  for (int k4 = 0; k4 < 32; ++k4) {
    const float4 wv = *(const float4*)(Wrow + k4 * 4);
#pragma unroll
    for (int rr = 0; rr < 16; ++rr) {
      const float4 ev = *(const float4*)&Elds[rg * 16 + rr][k4 * 4];
      acc[rr] = fmaf(wv.x, ev.x, acc[rr]);
      acc[rr] = fmaf(wv.y, ev.y, acc[rr]);
      acc[rr] = fmaf(wv.z, ev.z, acc[rr]);
      acc[rr] = fmaf(wv.w, ev.w, acc[rr]);
    }
  }
#pragma unroll
  for (int rr = 0; rr < 16; ++rr) {
    const int r = r0 + rg * 16 + rr;
    if (r < M) T[(size_t)r * DIM + o] = f2b(acc[rr]);
  }
}

// ---------------- P1b: tiny gate-bias tables
// Tkqd[i][o]=Eqd[i]@Wk[o,256:384] (bf16), Tkcd[i][o]=Ecd[i]@Wk[o,384:512] (bf16)
// Tp1c[e][o]=Ecorr[e]@Wp1[o,128:256]+bp1[o], Tp2c likewise, Tkc[e][o]=Ecorr[e]@Wk[o,128:256]+bk[o]
__global__ void small_tables_kernel(const float* __restrict__ Eqd, const float* __restrict__ Ecd,
                                    const float* __restrict__ Ecorr,
                                    const float* __restrict__ Wp1, const float* __restrict__ bp1,
                                    const float* __restrict__ Wp2, const float* __restrict__ bp2,
                                    const float* __restrict__ Wk, const float* __restrict__ bk,
                                    unsigned short* __restrict__ Tkqd, unsigned short* __restrict__ Tkcd,
                                    float* __restrict__ Tkc, float* __restrict__ Tp1c,
                                    float* __restrict__ Tp2c) {
  const int blk = blockIdx.x;
  const int tid = threadIdx.x;
  if (blk < 101) {
    const int o = tid & 127, half = tid >> 7;
    const float* e = (half ? Ecd : Eqd) + (size_t)blk * DIM;
    const float* wr = Wk + (size_t)o * 512 + (half ? 384 : 256);
    float a = 0.f;
    for (int k = 0; k < DIM; ++k) a = fmaf(e[k], wr[k], a);
    (half ? Tkcd : Tkqd)[blk * DIM + o] = f2b(a);
  } else {
    for (int idx = tid; idx < 768; idx += 256) {
      const int t = idx >> 8, e = (idx >> 7) & 1, o = idx & 127;
      const float* ec = Ecorr + e * DIM;
      const float* wr;
      float bias;
      float* dst;
      if (t == 0)      { wr = Wp1 + (size_t)o * 256 + 128; bias = bp1[o]; dst = Tp1c; }
      else if (t == 1) { wr = Wp2 + (size_t)o * 256 + 128; bias = bp2[o]; dst = Tp2c; }
      else             { wr = Wk  + (size_t)o * 512 + 128; bias = bk[o];  dst = Tkc;  }
      float a = bias;
      for (int k = 0; k < DIM; ++k) a = fmaf(ec[k], wr[k], a);
      dst[e * DIM + o] = a;
    }
  }
}

// ---------------- P2: x[b,s,:] = Tq[q]+Tc[c]+Tqd[qd]+Tcd[cd]+bx (bf16 out)
__global__ void build_x_kernel(const int* __restrict__ qs, const int* __restrict__ cs,
                               const int* __restrict__ qds, const int* __restrict__ cds,
                               const unsigned short* __restrict__ Tq, const unsigned short* __restrict__ Tc,
                               const unsigned short* __restrict__ Tqd, const unsigned short* __restrict__ Tcd,
                               const float* __restrict__ bx, unsigned short* __restrict__ xg) {
  const int r = blockIdx.x * 16 + (threadIdx.x >> 4);   // (b,s) flat row
  const int c8 = (threadIdx.x & 15) * 8;
  const int q = qs[r], c = cs[r], qd = qds[r], cd = cds[r];
  union U8 { uint4 v; unsigned short s[8]; };
  U8 vq, vc, vd, ve, o;
  vq.v = *(const uint4*)(Tq + (size_t)q * DIM + c8);
  vc.v = *(const uint4*)(Tc + (size_t)c * DIM + c8);
  vd.v = *(const uint4*)(Tqd + (size_t)qd * DIM + c8);
  ve.v = *(const uint4*)(Tcd + (size_t)cd * DIM + c8);
  const float4 bx0 = *(const float4*)(bx + c8);
  const float4 bx1 = *(const float4*)(bx + c8 + 4);
  float bb[8] = {bx0.x, bx0.y, bx0.z, bx0.w, bx1.x, bx1.y, bx1.z, bx1.w};
#pragma unroll
  for (int j = 0; j < 8; ++j) {
    const float s = b2f(vq.s[j]) + b2f(vc.s[j]) + b2f(vd.s[j]) + b2f(ve.s[j]) + bb[j];
    o.s[j] = f2b(s);
  }
  *(uint4*)(xg + (size_t)r * DIM + c8) = o.v;
}

// ---------------- P3: the recurrence. 64 blocks x 16 rows, 4 waves (32 cols each).
__global__ __launch_bounds__(256, 1) void scan_kernel(
    const unsigned short* __restrict__ xg, const float* __restrict__ h0,
    const float* __restrict__ Ws1, const float* __restrict__ bs1,
    const float* __restrict__ Ws2, const float* __restrict__ bs2,
    const float* __restrict__ Wp1, const float* __restrict__ Wp2,
    const float* __restrict__ Wk,
    const unsigned short* __restrict__ gTkqd, const unsigned short* __restrict__ gTkcd,
    const float* __restrict__ gTkc, const float* __restrict__ gTp1c, const float* __restrict__ gTp2c,
    const int* __restrict__ corr_seq, const int* __restrict__ qd_seq, const int* __restrict__ cd_seq,
    float* __restrict__ outp) {
  // stride 136 bf16 = 272B: 16B-aligned b128 frags, 2-way (free) bank aliasing
  __shared__ __align__(16) unsigned short Sbuf[16][136];  // s_in, pad unused
  __shared__ __align__(16) unsigned short Hbuf[16][136];  // h
  __shared__ __align__(16) unsigned short Pbuf[16][136];  // sdf; pad = per-row dot partials (4 floats)
  __shared__ __align__(16) unsigned short TkqdL[101 * DIM];
  __shared__ __align__(16) unsigned short TkcdL[101 * DIM];

  const int tid = threadIdx.x;
  const int w = tid >> 6;        // wave: cols [32w, 32w+32)
  const int L = tid & 63;
  const int q = L >> 4;          // quad
  const int m = L & 15;
  const int rbase = blockIdx.x << 4;

  for (int i = tid; i < (101 * DIM) / 8; i += 256) {
    ((uint4*)TkqdL)[i] = ((const uint4*)gTkqd)[i];
    ((uint4*)TkcdL)[i] = ((const uint4*)gTkcd)[i];
  }

  // register-resident B-fragments of the 5 in-scan weights (bf16)
  // B[k][n] = W[n][k]; lane: n = 32w+16T+m, k = kb*32 + q*8 + j
  short8 wf[5][2][4];
  {
    const float* Wptr[5] = {Ws1, Ws2, Wp1, Wp2, Wk};
    const int ldw[5] = {128, 128, 256, 256, 512};
#pragma unroll
    for (int M = 0; M < 5; ++M) {
#pragma unroll
      for (int T = 0; T < 2; ++T) {
        const int n = 32 * w + 16 * T + m;
#pragma unroll
        for (int kb = 0; kb < 4; ++kb) {
          const float* src = Wptr[M] + (size_t)n * ldw[M] + kb * 32 + q * 8;
          const float4 v0 = *(const float4*)src;
          const float4 v1 = *(const float4*)(src + 4);
          short8 f;
          f[0] = (short)f2b(v0.x); f[1] = (short)f2b(v0.y);
          f[2] = (short)f2b(v0.z); f[3] = (short)f2b(v0.w);
          f[4] = (short)f2b(v1.x); f[5] = (short)f2b(v1.y);
          f[6] = (short)f2b(v1.z); f[7] = (short)f2b(v1.w);
          wf[M][T][kb] = f;
        }
      }
    }
  }

  float bs1v[2], bs2v[2];
#pragma unroll
  for (int T = 0; T < 2; ++T) {
    const int n = 32 * w + 16 * T + m;
    bs1v[T] = bs1[n];
    bs2v[T] = bs2[n];
  }

  // init: h (fp32 regs, C-layout: row=q*4+i, col=32w+16T+m), Hbuf, Sbuf = x[:,0]-h
  float h[2][4];
#pragma unroll
  for (int T = 0; T < 2; ++T) {
    const int col = 32 * w + 16 * T + m;
#pragma unroll
    for (int i = 0; i < 4; ++i) {
      const int row = q * 4 + i;
      const int b = rbase + row;
      const float hv = h0[(size_t)b * DIM + col];
      h[T][i] = hv;
      const float xt = b2f(xg[((size_t)b * S_LEN) * DIM + col]);
      Hbuf[row][col] = f2b(hv);
      Sbuf[row][col] = f2b(xt - hv);
    }
  }
  if (tid < 16) outp[(size_t)(rbase + tid) * S_LEN + (S_LEN - 1)] = 0.0f;
  __syncthreads();

  for (int t = 0; t < S_LEN - 1; ++t) {
    // prefetch x[:, t+1] at C-layout positions
    unsigned short xnr[2][4];
#pragma unroll
    for (int T = 0; T < 2; ++T) {
      const int col = 32 * w + 16 * T + m;
#pragma unroll
      for (int i = 0; i < 4; ++i) {
        const int b = rbase + q * 4 + i;
        xnr[T][i] = xg[((size_t)b * S_LEN + t + 1) * DIM + col];
      }
    }
    // per-row indices + precomputed gate biases (depend only on t)
    int ci[4], qi[4], di[4];
#pragma unroll
    for (int i = 0; i < 4; ++i) {
      const int b = rbase + q * 4 + i;
      ci[i] = corr_seq[b * S_LEN + t];
      qi[i] = qd_seq[b * S_LEN + t];
      di[i] = cd_seq[b * S_LEN + t];
    }
    float gpre[2][4], tp1[2][4], tp2[2][4];
#pragma unroll
    for (int T = 0; T < 2; ++T) {
      const int col = 32 * w + 16 * T + m;
#pragma unroll
      for (int i = 0; i < 4; ++i) {
        gpre[T][i] = gTkc[ci[i] * DIM + col] + b2f(TkqdL[qi[i] * DIM + col]) + b2f(TkcdL[di[i] * DIM + col]);
        tp1[T][i] = gTp1c[ci[i] * DIM + col];
        tp2[T][i] = gTp2c[ci[i] * DIM + col];
      }
    }

    // phase A: a1 = s_in@Ws1.T, a2 = s_in@Ws2.T, c1 = h@Wkh.T
    short8 sf[4], hf[4];
#pragma unroll
    for (int kb = 0; kb < 4; ++kb) {
      sf[kb] = *(const short8*)&Sbuf[m][kb * 32 + q * 8];
      hf[kb] = *(const short8*)&Hbuf[m][kb * 32 + q * 8];
    }
    const f32x4 vzero = {0.0f, 0.0f, 0.0f, 0.0f};
    f32x4 a1[2] = {vzero, vzero}, a2[2] = {vzero, vzero}, c1a[2] = {vzero, vzero};
#pragma unroll
    for (int kb = 0; kb < 4; ++kb) {
#pragma unroll
      for (int T = 0; T < 2; ++T) {
        a1[T]  = __builtin_amdgcn_mfma_f32_16x16x32_bf16(sf[kb], wf[0][T][kb], a1[T], 0, 0, 0);
        a2[T]  = __builtin_amdgcn_mfma_f32_16x16x32_bf16(sf[kb], wf[1][T][kb], a2[T], 0, 0, 0);
        c1a[T] = __builtin_amdgcn_mfma_f32_16x16x32_bf16(hf[kb], wf[4][T][kb], c1a[T], 0, 0, 0);
      }
    }
    // sdf = sigmoid(a1+bs1)*tanh(a2+bs2) -> Pbuf (bf16)
#pragma unroll
    for (int T = 0; T < 2; ++T) {
      const int col = 32 * w + 16 * T + m;
#pragma unroll
      for (int i = 0; i < 4; ++i) {
        const float sg = fast_sigmoid(a1[T][i] + bs1v[T]);
        const float th = fast_tanh(a2[T][i] + bs2v[T]);
        Pbuf[q * 4 + i][col] = f2b(sg * th);
      }
    }
    __syncthreads();

    // phase B: b1 = sdf@Wp1s.T, b2 = sdf@Wp2s.T; gates; h update; dot
    short8 pf[4];
#pragma unroll
    for (int kb = 0; kb < 4; ++kb) pf[kb] = *(const short8*)&Pbuf[m][kb * 32 + q * 8];
    f32x4 p1a[2] = {vzero, vzero}, p2a[2] = {vzero, vzero};
#pragma unroll
    for (int kb = 0; kb < 4; ++kb) {
#pragma unroll
      for (int T = 0; T < 2; ++T) {
        p1a[T] = __builtin_amdgcn_mfma_f32_16x16x32_bf16(pf[kb], wf[2][T][kb], p1a[T], 0, 0, 0);
        p2a[T] = __builtin_amdgcn_mfma_f32_16x16x32_bf16(pf[kb], wf[3][T][kb], p2a[T], 0, 0, 0);
      }
    }
    float dotp[4] = {0.0f, 0.0f, 0.0f, 0.0f};
#pragma unroll
    for (int T = 0; T < 2; ++T) {
      const int col = 32 * w + 16 * T + m;
#pragma unroll
      for (int i = 0; i < 4; ++i) {
        const int row = q * 4 + i;
        const float g = fast_sigmoid(c1a[T][i] + gpre[T][i]);
        const float pka = fast_sigmoid(p1a[T][i] + tp1[T][i]) * fast_tanh(p2a[T][i] + tp2[T][i]);
        const float hn = g * h[T][i] + (1.0f - g) * pka;
        h[T][i] = hn;
        const float xn = b2f(xnr[T][i]);
        dotp[i] += xn * hn;
        Sbuf[row][col] = f2b(xn - hn);   // s_in for t+1
        Hbuf[row][col] = f2b(hn);
      }
    }
    // reduce dot over the 16 m-lanes (stays in quad), stash per-wave partials in Pbuf pad
#pragma unroll
    for (int off = 1; off <= 8; off <<= 1) {
#pragma unroll
      for (int i = 0; i < 4; ++i) dotp[i] += __shfl_xor(dotp[i], off, 64);
    }
    if (m == 0) {
#pragma unroll
      for (int i = 0; i < 4; ++i) *(float*)&Pbuf[q * 4 + i][128 + 2 * w] = dotp[i];
    }
    __syncthreads();
    if (tid < 16) {
      const float d = *(const float*)&Pbuf[tid][128] + *(const float*)&Pbuf[tid][130] +
                      *(const float*)&Pbuf[tid][132] + *(const float*)&Pbuf[tid][134];
      outp[(size_t)(rbase + tid) * S_LEN + t] = fast_sigmoid(d);
    }
  }
}

extern "C" void kernel_launch(void* const* d_in, const int* in_sizes, int n_in,
                              void* d_out, int out_size, void* d_ws, size_t ws_size,
                              hipStream_t stream) {
  const int* qs    = (const int*)d_in[0];
  const int* cs    = (const int*)d_in[1];
  const int* qds   = (const int*)d_in[2];
  const int* cds   = (const int*)d_in[3];
  const int* corr  = (const int*)d_in[4];
  const float* Eq    = (const float*)d_in[5];
  const float* Ec    = (const float*)d_in[6];
  const float* Eqd   = (const float*)d_in[7];
  const float* Ecd   = (const float*)d_in[8];
  const float* Ecorr = (const float*)d_in[9];
  const float* Wx  = (const float*)d_in[10];
  const float* bx  = (const float*)d_in[11];
  const float* Ws1 = (const float*)d_in[12];
  const float* bs1 = (const float*)d_in[13];
  const float* Ws2 = (const float*)d_in[14];
  const float* bs2 = (const float*)d_in[15];
  const float* Wp1 = (const float*)d_in[16];
  const float* bp1 = (const float*)d_in[17];
  const float* Wp2 = (const float*)d_in[18];
  const float* bp2 = (const float*)d_in[19];
  const float* Wk  = (const float*)d_in[20];
  const float* bk  = (const float*)d_in[21];
  const float* h0  = (const float*)d_in[22];

  char* ws = (char*)d_ws;
  size_t off = 0;
  auto alloc = [&](size_t bytes) {
    void* p = ws + off;
    off = (off + bytes + 255) & ~(size_t)255;
    return p;
  };
  unsigned short* Tq   = (unsigned short*)alloc((size_t)50000 * DIM * 2);
  unsigned short* Tc   = (unsigned short*)alloc((size_t)1000 * DIM * 2);
  unsigned short* Tqd  = (unsigned short*)alloc((size_t)101 * DIM * 2);
  unsigned short* Tcd  = (unsigned short*)alloc((size_t)101 * DIM * 2);
  unsigned short* Tkqd = (unsigned short*)alloc((size_t)101 * DIM * 2);
  unsigned short* Tkcd = (unsigned short*)alloc((size_t)101 * DIM * 2);
  float* Tkc  = (float*)alloc((size_t)2 * DIM * 4);
  float* Tp1c = (float*)alloc((size_t)2 * DIM * 4);
  float* Tp2c = (float*)alloc((size_t)2 * DIM * 4);
  unsigned short* X = (unsigned short*)alloc((size_t)NBATCH * S_LEN * DIM * 2);

  proj_table_kernel<<<(50000 + 31) / 32, 256, 0, stream>>>(Eq, 50000, Wx, 512, 0, Tq);
  proj_table_kernel<<<(1000 + 31) / 32, 256, 0, stream>>>(Ec, 1000, Wx, 512, 128, Tc);
  proj_table_kernel<<<4, 256, 0, stream>>>(Eqd, 101, Wx, 512, 256, Tqd);
  proj_table_kernel<<<4, 256, 0, stream>>>(Ecd, 101, Wx, 512, 384, Tcd);
  small_tables_kernel<<<102, 256, 0, stream>>>(Eqd, Ecd, Ecorr, Wp1, bp1, Wp2, bp2, Wk, bk,
                                               Tkqd, Tkcd, Tkc, Tp1c, Tp2c);
  build_x_kernel<<<(NBATCH * S_LEN) / 16, 256, 0, stream>>>(qs, cs, qds, cds, Tq, Tc, Tqd, Tcd, bx, X);
  scan_kernel<<<64, 256, 0, stream>>>(X, h0, Ws1, bs1, Ws2, bs2, Wp1, Wp2, Wk,
                                      Tkqd, Tkcd, Tkc, Tp1c, Tp2c, corr, qds, cds, (float*)d_out);
}